// Round 1
// baseline (133.880 us; speedup 1.0000x reference)
//
#include <hip/hip_runtime.h>

#define HIDDEN 128

// out[e] = dot(edge_hidden[e], W[0:128]) + dot(node[src[e]], W[128:256])
//        + dot(node[dst[e]], W[256:384]) + b
// 32 lanes cooperate on one edge: lane reads float4 at offset lane*4 of each
// 128-float row (512 B coalesced), dots against the matching W chunk, then a
// 5-step shuffle reduction within the 32-lane group.
__global__ __launch_bounds__(256)
void decoder_edge_kernel(const float* __restrict__ node_hidden,
                         const float* __restrict__ edge_hidden,
                         const int*   __restrict__ edge_index, // [2][n_edges]
                         const float* __restrict__ W,          // [384]
                         const float* __restrict__ b,          // [1]
                         float* __restrict__ out,              // [n_edges]
                         int n_edges) {
    const int tid  = blockIdx.x * blockDim.x + threadIdx.x;
    const int edge = tid >> 5;          // 32 lanes per edge
    const int lane = tid & 31;
    if (edge >= n_edges) return;

    const int s = edge_index[edge];             // src row
    const int d = edge_index[n_edges + edge];   // dst row

    const float4 e4 = reinterpret_cast<const float4*>(edge_hidden + (size_t)edge * HIDDEN)[lane];
    const float4 s4 = reinterpret_cast<const float4*>(node_hidden + (size_t)s    * HIDDEN)[lane];
    const float4 d4 = reinterpret_cast<const float4*>(node_hidden + (size_t)d    * HIDDEN)[lane];

    const float4 we = reinterpret_cast<const float4*>(W)[lane];
    const float4 ws = reinterpret_cast<const float4*>(W + HIDDEN)[lane];
    const float4 wd = reinterpret_cast<const float4*>(W + 2 * HIDDEN)[lane];

    float acc = e4.x * we.x + e4.y * we.y + e4.z * we.z + e4.w * we.w
              + s4.x * ws.x + s4.y * ws.y + s4.z * ws.z + s4.w * ws.w
              + d4.x * wd.x + d4.y * wd.y + d4.z * wd.z + d4.w * wd.w;

    // reduce across the 32-lane group
    #pragma unroll
    for (int off = 16; off > 0; off >>= 1)
        acc += __shfl_down(acc, off, 32);

    if (lane == 0)
        out[edge] = acc + b[0];
}

extern "C" void kernel_launch(void* const* d_in, const int* in_sizes, int n_in,
                              void* d_out, int out_size, void* d_ws, size_t ws_size,
                              hipStream_t stream) {
    const float* node_hidden = (const float*)d_in[0];
    const float* edge_hidden = (const float*)d_in[1];
    const int*   edge_index  = (const int*)d_in[2];
    const float* W           = (const float*)d_in[3];
    const float* b           = (const float*)d_in[4];
    float* out = (float*)d_out;

    const int n_edges = in_sizes[2] / 2;

    const int threads = 256;
    const int edges_per_block = threads / 32;
    const int blocks = (n_edges + edges_per_block - 1) / edges_per_block;

    decoder_edge_kernel<<<blocks, threads, 0, stream>>>(
        node_hidden, edge_hidden, edge_index, W, b, out, n_edges);
}

// Round 2
// 104.575 us; speedup vs baseline: 1.2802x; 1.2802x over previous
//
#include <hip/hip_runtime.h>

#define HIDDEN 128

// Phase 1: per-node dot products against W_s and W_d.
// ns[n] = dot(node[n], W[128:256]);  nd[n] = dot(node[n], W[256:384])
// 32 lanes per node, float4 per lane, shuffle reduce.
__global__ __launch_bounds__(256)
void node_dots_kernel(const float* __restrict__ node_hidden,
                      const float* __restrict__ W,   // [384]
                      float* __restrict__ ns,        // [n_nodes]
                      float* __restrict__ nd,        // [n_nodes]
                      int n_nodes) {
    const int tid  = blockIdx.x * blockDim.x + threadIdx.x;
    const int node = tid >> 5;
    const int lane = tid & 31;
    if (node >= n_nodes) return;

    const float4 v  = reinterpret_cast<const float4*>(node_hidden + (size_t)node * HIDDEN)[lane];
    const float4 ws = reinterpret_cast<const float4*>(W + HIDDEN)[lane];
    const float4 wd = reinterpret_cast<const float4*>(W + 2 * HIDDEN)[lane];

    float as = v.x * ws.x + v.y * ws.y + v.z * ws.z + v.w * ws.w;
    float ad = v.x * wd.x + v.y * wd.y + v.z * wd.z + v.w * wd.w;

    #pragma unroll
    for (int off = 16; off > 0; off >>= 1) {
        as += __shfl_down(as, off, 32);
        ad += __shfl_down(ad, off, 32);
    }
    if (lane == 0) {
        ns[node] = as;
        nd[node] = ad;
    }
}

// Phase 2: per-edge. out[e] = dot(edge_hidden[e], W[0:128]) + ns[src] + nd[dst] + b.
// The ns/nd tables are 800 KB total -> resident in every XCD's 4 MiB L2, so
// the random gather is cheap. edge_hidden is a pure coalesced stream.
__global__ __launch_bounds__(256)
void edge_out_kernel(const float* __restrict__ edge_hidden,
                     const int*   __restrict__ edge_index, // [2][n_edges]
                     const float* __restrict__ W,          // [384]
                     const float* __restrict__ b,          // [1]
                     const float* __restrict__ ns,
                     const float* __restrict__ nd,
                     float* __restrict__ out,
                     int n_edges) {
    const int tid  = blockIdx.x * blockDim.x + threadIdx.x;
    const int edge = tid >> 5;
    const int lane = tid & 31;
    if (edge >= n_edges) return;

    const float4 e4 = reinterpret_cast<const float4*>(edge_hidden + (size_t)edge * HIDDEN)[lane];
    const float4 we = reinterpret_cast<const float4*>(W)[lane];

    float acc = e4.x * we.x + e4.y * we.y + e4.z * we.z + e4.w * we.w;

    #pragma unroll
    for (int off = 16; off > 0; off >>= 1)
        acc += __shfl_down(acc, off, 32);

    if (lane == 0) {
        const int s = edge_index[edge];
        const int d = edge_index[n_edges + edge];
        out[edge] = acc + ns[s] + nd[d] + b[0];
    }
}

// Fallback (round-1 kernel) in case ws_size is too small for the node tables.
__global__ __launch_bounds__(256)
void decoder_edge_fused_kernel(const float* __restrict__ node_hidden,
                               const float* __restrict__ edge_hidden,
                               const int*   __restrict__ edge_index,
                               const float* __restrict__ W,
                               const float* __restrict__ b,
                               float* __restrict__ out,
                               int n_edges) {
    const int tid  = blockIdx.x * blockDim.x + threadIdx.x;
    const int edge = tid >> 5;
    const int lane = tid & 31;
    if (edge >= n_edges) return;

    const int s = edge_index[edge];
    const int d = edge_index[n_edges + edge];

    const float4 e4 = reinterpret_cast<const float4*>(edge_hidden + (size_t)edge * HIDDEN)[lane];
    const float4 s4 = reinterpret_cast<const float4*>(node_hidden + (size_t)s    * HIDDEN)[lane];
    const float4 d4 = reinterpret_cast<const float4*>(node_hidden + (size_t)d    * HIDDEN)[lane];

    const float4 we = reinterpret_cast<const float4*>(W)[lane];
    const float4 ws = reinterpret_cast<const float4*>(W + HIDDEN)[lane];
    const float4 wd = reinterpret_cast<const float4*>(W + 2 * HIDDEN)[lane];

    float acc = e4.x * we.x + e4.y * we.y + e4.z * we.z + e4.w * we.w
              + s4.x * ws.x + s4.y * ws.y + s4.z * ws.z + s4.w * ws.w
              + d4.x * wd.x + d4.y * wd.y + d4.z * wd.z + d4.w * wd.w;

    #pragma unroll
    for (int off = 16; off > 0; off >>= 1)
        acc += __shfl_down(acc, off, 32);

    if (lane == 0)
        out[edge] = acc + b[0];
}

extern "C" void kernel_launch(void* const* d_in, const int* in_sizes, int n_in,
                              void* d_out, int out_size, void* d_ws, size_t ws_size,
                              hipStream_t stream) {
    const float* node_hidden = (const float*)d_in[0];
    const float* edge_hidden = (const float*)d_in[1];
    const int*   edge_index  = (const int*)d_in[2];
    const float* W           = (const float*)d_in[3];
    const float* b           = (const float*)d_in[4];
    float* out = (float*)d_out;

    const int n_nodes = in_sizes[0] / HIDDEN;
    const int n_edges = in_sizes[2] / 2;

    const size_t need = 2 * (size_t)n_nodes * sizeof(float);
    if (ws_size >= need) {
        float* ns = (float*)d_ws;
        float* nd = ns + n_nodes;

        {
            const int threads = 256;
            const int nodes_per_block = threads / 32;
            const int blocks = (n_nodes + nodes_per_block - 1) / nodes_per_block;
            node_dots_kernel<<<blocks, threads, 0, stream>>>(node_hidden, W, ns, nd, n_nodes);
        }
        {
            const int threads = 256;
            const int edges_per_block = threads / 32;
            const int blocks = (n_edges + edges_per_block - 1) / edges_per_block;
            edge_out_kernel<<<blocks, threads, 0, stream>>>(edge_hidden, edge_index, W, b,
                                                            ns, nd, out, n_edges);
        }
    } else {
        const int threads = 256;
        const int edges_per_block = threads / 32;
        const int blocks = (n_edges + edges_per_block - 1) / edges_per_block;
        decoder_edge_fused_kernel<<<blocks, threads, 0, stream>>>(
            node_hidden, edge_hidden, edge_index, W, b, out, n_edges);
    }
}